// Round 4
// baseline (318.977 us; speedup 1.0000x reference)
//
#include <hip/hip_runtime.h>
#include <cstdint>
#include <cstddef>

// Problem constants (from reference): B=16, S=4096, C=512, A=0.5
#define PB 16
#define PS 4096
#define PC 512

#define RPB 32           // rows per block in k1
#define PANEL 64         // columns per panel
#define NPANEL (PC / PANEL)            // 8
#define LSTRIDE 68       // 64 + 4 pad: float4-aligned, <=2-way bank aliasing

// ---------------------------------------------------------------------------
// K0: zero the accumulators k1 atomicAdds into.
// ---------------------------------------------------------------------------
__global__ __launch_bounds__(256) void k0_init(int* __restrict__ nCnt,
                                               float* __restrict__ colsum,
                                               float* __restrict__ Lsum) {
    int i = blockIdx.x * 256 + threadIdx.x;
    if (i < PB * PC) { nCnt[i] = 0; colsum[i] = 0.0f; }
    if (i < PB) Lsum[i] = 0.0f;
}

// ---------------------------------------------------------------------------
// K1: LDS-staged streaming pass. 2048 blocks (8/CU), 32 rows/block, 8 panels
// of 64 cols, double-buffered. 2 float4 prefetches/thread -> 64 KB/CU in
// flight (Little's law needs ~22 KB at ~900cy) -> HBM-paced, not latency-bound
// (R3: 512 blocks, 1 prefetch -> 20% occupancy, 835 GB/s).
// Thread t>>3 = row, t&7 = col-octet; online softmax in registers, no
// cross-lane ops until the 3-level merge at the end.
// ---------------------------------------------------------------------------
__global__ __launch_bounds__(256, 8) void k1_rows(const float* __restrict__ pred,
                                                  const int* __restrict__ target,
                                                  int* __restrict__ am,
                                                  float* __restrict__ lse,
                                                  int* __restrict__ nCnt,
                                                  float* __restrict__ colsum,
                                                  float* __restrict__ Lsum) {
    __shared__ float tile[2][RPB * LSTRIDE];   // 2*32*68*4 = 17408 B
    __shared__ float colLDS[PC];               // 2048 B

    const int t = threadIdx.x;
    const int rowBase = blockIdx.x * RPB;
    const int b = rowBase >> 12;               // PS = 4096
    const float* base = pred + (size_t)rowBase * PC;

    colLDS[t] = 0.0f; colLDS[t + 256] = 0.0f;

    // Loader: panel = 32 rows x 16 float4-chunks = 512 chunks; thread owns 2.
    const float* gp[2];
    int ldsOff[2];
    #pragma unroll
    for (int j = 0; j < 2; ++j) {
        int g = j * 256 + t;
        int r = g >> 4, c4 = g & 15;
        gp[j] = base + (size_t)r * PC + 4 * c4;
        ldsOff[j] = r * LSTRIDE + 4 * c4;
    }

    float4 reg[2];
    #pragma unroll
    for (int j = 0; j < 2; ++j) reg[j] = *(const float4*)(gp[j]);   // panel 0

    const int rt = t >> 3;      // row within block (0..31)
    const int h = t & 7;        // col octet (cols 8h..8h+7 of each panel)
    float mval = -3.4e38f;
    float ssum = 0.0f;
    int midx = 0;

    for (int p = 0; p < NPANEL; ++p) {
        float* tb = tile[p & 1];
        #pragma unroll
        for (int j = 0; j < 2; ++j) {
            float* d = tb + ldsOff[j];
            *(float4*)d = reg[j];
        }
        __syncthreads();

        if (p + 1 < NPANEL) {
            #pragma unroll
            for (int j = 0; j < 2; ++j)
                reg[j] = *(const float4*)(gp[j] + (p + 1) * PANEL);   // prefetch
        }

        // row scan: 8 cols of this thread's row (two float4 LDS reads)
        const float* rowp = tb + rt * LSTRIDE + 8 * h;
        float4 a = *(const float4*)(rowp);
        float4 c = *(const float4*)(rowp + 4);
        float v0=a.x, v1=a.y, v2=a.z, v3=a.w, v4=c.x, v5=c.y, v6=c.z, v7=c.w;

        // first-max of 8 (tree, earliest index wins on tie)
        float pm = v0; int pi = 0;
        if (v1 > pm) { pm = v1; pi = 1; }
        if (v2 > pm) { pm = v2; pi = 2; }
        if (v3 > pm) { pm = v3; pi = 3; }
        if (v4 > pm) { pm = v4; pi = 4; }
        if (v5 > pm) { pm = v5; pi = 5; }
        if (v6 > pm) { pm = v6; pi = 6; }
        if (v7 > pm) { pm = v7; pi = 7; }

        if (pm > mval) {
            ssum *= __expf(mval - pm);
            mval = pm;
            midx = p * PANEL + 8 * h + pi;   // strict > : first max overall
        }
        ssum += __expf(v0 - mval) + __expf(v1 - mval) + __expf(v2 - mval)
              + __expf(v3 - mval) + __expf(v4 - mval) + __expf(v5 - mval)
              + __expf(v6 - mval) + __expf(v7 - mval);

        // column partials: thread t sums 8 rows of panel-col (t&63)
        {
            int cl = t & 63, g2 = t >> 6;
            const float* colp = tb + (8 * g2) * LSTRIDE + cl;
            float part = 0.0f;
            #pragma unroll
            for (int r = 0; r < 8; ++r) part += colp[r * LSTRIDE];
            atomicAdd(&colLDS[p * PANEL + cl], part);   // 4-way LDS atomic
        }
        // single barrier per panel is safe: reads of panel p finish before
        // any thread can pass barrier(p+1), which precedes writes of p+2.
    }

    // merge 8 per-thread states of each row (lanes t..t^7, same wave)
    #pragma unroll
    for (int off = 1; off < 8; off <<= 1) {
        float om = __shfl_xor(mval, off, 64);
        float os = __shfl_xor(ssum, off, 64);
        int   oi = __shfl_xor(midx, off, 64);
        float M = fmaxf(mval, om);
        int nI = (om > mval || (om == mval && oi < midx)) ? oi : midx;
        float nS = ssum * __expf(mval - M) + os * __expf(om - M);
        mval = M; midx = nI; ssum = nS;
    }
    float lse_v = mval + __logf(ssum);

    if (h == 0) {
        int grow = rowBase + rt;
        lse[grow] = lse_v;
        am[grow] = midx;
        int tg = target[grow];
        atomicAdd(&nCnt[(b << 9) + tg], 1);
    }

    // per-batch lse sum: wave reduce then one atomic per wave
    float lv = (h == 0) ? lse_v : 0.0f;
    #pragma unroll
    for (int off = 1; off < 64; off <<= 1) lv += __shfl_xor(lv, off, 64);
    if ((t & 63) == 0) atomicAdd(&Lsum[b], lv);

    __syncthreads();
    atomicAdd(&colsum[(b << 9) + t], colLDS[t]);
    atomicAdd(&colsum[(b << 9) + t + 256], colLDS[t + 256]);
}

// ---------------------------------------------------------------------------
// K23: fused per-batch scan + scatter. One block (512 threads) per batch.
// Block 0 zeroes acc/done for K45.
// ---------------------------------------------------------------------------
__global__ __launch_bounds__(512) void k23(const int* __restrict__ nCnt,
                                           const int* __restrict__ target,
                                           const int* __restrict__ am,
                                           int* __restrict__ offs,
                                           int* __restrict__ bucket,
                                           float* __restrict__ acc,
                                           int* __restrict__ done) {
    int b = blockIdx.x;
    int t = threadIdx.x;
    __shared__ int sc[PC];
    __shared__ int cur[PC];
    int x = nCnt[(b << 9) + t];
    sc[t] = x;
    __syncthreads();
    for (int off = 1; off < PC; off <<= 1) {
        int v = (t >= off) ? sc[t - off] : 0;
        __syncthreads();
        sc[t] += v;
        __syncthreads();
    }
    int g = (b << 12) + (sc[t] - x);   // global exclusive offset
    offs[(b << 9) + t] = g;
    cur[t] = g;
    if (b == 0 && t < 3) {
        if (t < 2) acc[t] = 0.0f;
        else *done = 0;
    }
    __syncthreads();
    for (int i = t; i < PS; i += 512) {
        int gi = (b << 12) + i;
        int tg = target[gi];
        int a = am[gi];
        int pos = atomicAdd(&cur[tg], 1);
        bucket[pos] = i | (a << 12);   // s in 12 bits, am class above
    }
}

// ---------------------------------------------------------------------------
// K45: one thread per (b,t) pair; mode of am over the bucket (tie -> smallest
// class), eq/ne sums, val; wave-reduce into acc; last block writes out.
// ---------------------------------------------------------------------------
__global__ __launch_bounds__(64) void k45(const float* __restrict__ pred,
                                          const int* __restrict__ nCnt,
                                          const int* __restrict__ offs,
                                          const int* __restrict__ bucket,
                                          const float* __restrict__ lse,
                                          const float* __restrict__ colsum,
                                          const float* __restrict__ Lsum,
                                          float* __restrict__ acc,
                                          int* __restrict__ done,
                                          float* __restrict__ out) {
    __shared__ int cache[64][33];
    int pair = blockIdx.x * 64 + threadIdx.x;   // < B*C
    int b = pair >> 9;
    int k = nCnt[pair];
    int start = offs[pair];

    float val = 0.0f;
    int keep = 0;

    if (k > 0) {
        int kc = (k < 32) ? k : 32;
        for (int i = 0; i < kc; ++i)
            cache[threadIdx.x][i] = bucket[start + i];

        int bc = 0, bvv = 0;
        if (k <= 32) {
            for (int i = 0; i < k; ++i) {
                int v = cache[threadIdx.x][i] >> 12;
                int c = 0;
                for (int j = 0; j < k; ++j) c += ((cache[threadIdx.x][j] >> 12) == v) ? 1 : 0;
                if (c > bc || (c == bc && v < bvv)) { bc = c; bvv = v; }
            }
        } else {
            for (int i = 0; i < k; ++i) {
                int v = bucket[start + i] >> 12;
                int c = 0;
                for (int j = 0; j < k; ++j)
                    c += ((bucket[start + j] >> 12) == v) ? 1 : 0;
                if (c > bc || (c == bc && v < bvv)) { bc = c; bvv = v; }
            }
        }
        int m = bvv;

        float lseSum = 0.0f, ep = 0.0f;
        for (int i = 0; i < k; ++i) {
            int e = (i < 32) ? cache[threadIdx.x][i] : bucket[start + i];
            int s = e & (PS - 1);
            lseSum += lse[(b << 12) + s];
            ep += pred[(((size_t)(b << 12)) + s) * PC + m];
        }
        float eq_sum = lseSum - ep;
        float total_term = Lsum[b] - colsum[(b << 9) + m];
        float ne_sum = total_term - eq_sum;
        float nf = (float)k;
        float eq_loss = eq_sum / fmaxf(nf, 1.0f);
        float ne_mean = ne_sum / fmaxf((float)PS - nf, 1.0f);
        float ne_loss = 1.0f / ((ne_mean != 0.0f) ? ne_mean : 1.0f);
        val = 0.5f * eq_loss + 0.5f * ne_loss;
        keep = (val != 0.0f) ? 1 : 0;
    }

    float vs = keep ? val : 0.0f;
    float ks = (float)keep;
    #pragma unroll
    for (int off = 1; off < 64; off <<= 1) {
        vs += __shfl_xor(vs, off, 64);
        ks += __shfl_xor(ks, off, 64);
    }
    if (threadIdx.x == 0) {
        atomicAdd(&acc[0], vs);
        atomicAdd(&acc[1], ks);
        __threadfence();
        int d = atomicAdd(done, 1);
        if (d == (int)gridDim.x - 1) {
            __threadfence();
            float a0 = atomicAdd(&acc[0], 0.0f);
            float a1 = atomicAdd(&acc[1], 0.0f);
            out[0] = a0 / fmaxf(a1, 1.0f);
        }
    }
}

extern "C" void kernel_launch(void* const* d_in, const int* in_sizes, int n_in,
                              void* d_out, int out_size, void* d_ws, size_t ws_size,
                              hipStream_t stream) {
    const float* pred = (const float*)d_in[0];   // (B,S,C) f32
    const int* target = (const int*)d_in[1];     // (B,S) int
    float* out = (float*)d_out;

    char* w = (char*)d_ws;
    int*   am     = (int*)(w + 0);          // B*S ints   = 256 KiB
    float* lse    = (float*)(w + 262144);   // B*S floats = 256 KiB
    int*   bucket = (int*)(w + 524288);     // B*S ints   = 256 KiB
    int*   nCnt   = (int*)(w + 786432);     // B*C ints   =  32 KiB
    int*   offs   = (int*)(w + 819200);     // B*C ints   =  32 KiB
    float* colsum = (float*)(w + 851968);   // B*C floats =  32 KiB
    float* Lsum   = (float*)(w + 884736);   // B floats
    float* acc    = (float*)(w + 884800);   // 2 floats
    int*   done   = (int*)(w + 884808);     // 1 int

    k0_init<<<32, 256, 0, stream>>>(nCnt, colsum, Lsum);
    k1_rows<<<(PB * PS) / RPB, 256, 0, stream>>>(pred, target, am, lse, nCnt, colsum, Lsum);
    k23<<<PB, 512, 0, stream>>>(nCnt, target, am, offs, bucket, acc, done);
    k45<<<(PB * PC) / 64, 64, 0, stream>>>(pred, nCnt, offs, bucket, lse,
                                           colsum, Lsum, acc, done, out);
}

// Round 5
// 220.648 us; speedup vs baseline: 1.4456x; 1.4456x over previous
//
#include <hip/hip_runtime.h>
#include <cstdint>
#include <cstddef>

// Problem constants (from reference): B=16, S=4096, C=512, A=0.5
#define PB 16
#define PS 4096
#define PC 512

// ---------------------------------------------------------------------------
// K0: zero colsum + acc + done (d_ws is poisoned 0xAA before every launch).
// ---------------------------------------------------------------------------
__global__ __launch_bounds__(256) void k0_init(float* __restrict__ colsum,
                                               float* __restrict__ acc,
                                               int* __restrict__ done) {
    int i = blockIdx.x * 256 + threadIdx.x;
    if (i < PB * PC) colsum[i] = 0.0f;
    if (i == 0) { acc[0] = 0.0f; acc[1] = 0.0f; *done = 0; }
}

// ---------------------------------------------------------------------------
// K1: register-direct streaming pass. 1024 blocks x 256 thr; each wave owns
// 4 rows and issues all 8 float4 loads up front (8 KB in flight/wave;
// 16 waves/CU -> ~128 KB/CU, far above the ~9 KB Little's-law floor).
// The 4 rows' butterfly reductions run in lockstep (ILP=4) to hide shuffle
// latency -- the serial-chain wall that sank R1/R2. No barriers, no LDS in
// the hot path (the panel-synchronized LDS staging of R3/R4 never sustained
// HBM: all waves drained vmcnt(0) at each panel barrier together).
// NOTE: no __launch_bounds__ min-waves -- R4 showed VGPR squeeze serializes
// the loads (VGPR 32 -> 1 in flight -> 507 GB/s).
// ---------------------------------------------------------------------------
__global__ __launch_bounds__(256) void k1_rows(const float* __restrict__ pred,
                                               int* __restrict__ am,
                                               float* __restrict__ lse,
                                               float* __restrict__ colsum) {
    const int t = threadIdx.x, w = t >> 6, l = t & 63;
    const int rowBase = blockIdx.x * 16 + w * 4;   // 4 consecutive rows per wave
    const int b = rowBase >> 12;                   // PS = 4096
    const float* base = pred + (size_t)rowBase * PC + 4 * l;

    // 8 independent coalesced loads (lane l -> bytes 16l..16l+15 of each half-row)
    float4 va[4], vb[4];
    #pragma unroll
    for (int r = 0; r < 4; ++r) {
        va[r] = *(const float4*)(base + r * PC);
        vb[r] = *(const float4*)(base + r * PC + 256);
    }

    // lane-local argmax over 8 elements per row (earliest index wins: strict >)
    float mv[4]; int mi[4];
    #pragma unroll
    for (int r = 0; r < 4; ++r) {
        float m = va[r].x; int i0 = 4 * l;
        if (va[r].y > m) { m = va[r].y; i0 = 4 * l + 1; }
        if (va[r].z > m) { m = va[r].z; i0 = 4 * l + 2; }
        if (va[r].w > m) { m = va[r].w; i0 = 4 * l + 3; }
        if (vb[r].x > m) { m = vb[r].x; i0 = 256 + 4 * l; }
        if (vb[r].y > m) { m = vb[r].y; i0 = 256 + 4 * l + 1; }
        if (vb[r].z > m) { m = vb[r].z; i0 = 256 + 4 * l + 2; }
        if (vb[r].w > m) { m = vb[r].w; i0 = 256 + 4 * l + 3; }
        mv[r] = m; mi[r] = i0;
    }

    // 4 interleaved butterflies: (max, min-index-on-tie) is assoc+comm
    #pragma unroll
    for (int off = 1; off < 64; off <<= 1) {
        #pragma unroll
        for (int r = 0; r < 4; ++r) {
            float ov = __shfl_xor(mv[r], off, 64);
            int   oi = __shfl_xor(mi[r], off, 64);
            if (ov > mv[r] || (ov == mv[r] && oi < mi[r])) { mv[r] = ov; mi[r] = oi; }
        }
    }

    // exp sums (mv[r] is now the true row max)
    float ss[4];
    #pragma unroll
    for (int r = 0; r < 4; ++r) {
        ss[r] = __expf(va[r].x - mv[r]) + __expf(va[r].y - mv[r])
              + __expf(va[r].z - mv[r]) + __expf(va[r].w - mv[r])
              + __expf(vb[r].x - mv[r]) + __expf(vb[r].y - mv[r])
              + __expf(vb[r].z - mv[r]) + __expf(vb[r].w - mv[r]);
    }
    #pragma unroll
    for (int off = 1; off < 64; off <<= 1) {
        #pragma unroll
        for (int r = 0; r < 4; ++r) ss[r] += __shfl_xor(ss[r], off, 64);
    }

    float l0 = mv[0] + __logf(ss[0]);
    float l1 = mv[1] + __logf(ss[1]);
    float l2 = mv[2] + __logf(ss[2]);
    float l3 = mv[3] + __logf(ss[3]);

    if (l == 0) {
        *(float4*)(lse + rowBase) = make_float4(l0, l1, l2, l3);   // 16B aligned
        *(int4*)(am + rowBase) = make_int4(mi[0], mi[1], mi[2], mi[3]);
    }

    // column sums: lane l owns cols {4l..4l+3, 256+4l..256+4l+3} of all 4 rows
    float cs0 = va[0].x + va[1].x + va[2].x + va[3].x;
    float cs1 = va[0].y + va[1].y + va[2].y + va[3].y;
    float cs2 = va[0].z + va[1].z + va[2].z + va[3].z;
    float cs3 = va[0].w + va[1].w + va[2].w + va[3].w;
    float cs4 = vb[0].x + vb[1].x + vb[2].x + vb[3].x;
    float cs5 = vb[0].y + vb[1].y + vb[2].y + vb[3].y;
    float cs6 = vb[0].z + vb[1].z + vb[2].z + vb[3].z;
    float cs7 = vb[0].w + vb[1].w + vb[2].w + vb[3].w;

    __shared__ float lds[4][PC];   // 8 KB
    lds[w][4 * l + 0] = cs0; lds[w][4 * l + 1] = cs1;
    lds[w][4 * l + 2] = cs2; lds[w][4 * l + 3] = cs3;
    lds[w][256 + 4 * l + 0] = cs4; lds[w][256 + 4 * l + 1] = cs5;
    lds[w][256 + 4 * l + 2] = cs6; lds[w][256 + 4 * l + 3] = cs7;
    __syncthreads();
    for (int c = t; c < PC; c += 256) {
        float s = lds[0][c] + lds[1][c] + lds[2][c] + lds[3][c];
        atomicAdd(&colsum[(b << 9) + c], s);   // all 4 waves share b
    }
}

// ---------------------------------------------------------------------------
// K_TAIL: one block (512 threads) per batch; everything batch-local in LDS.
//   pass1: load target/am/lse coalesced -> LDS, histogram, Lsum
//   scan -> bucket offsets; scatter (LDS cursors) -> sbucket
//   pairs: thread t = class t: mode m (tie -> smallest class), eq/ne sums,
//          val/keep; block reduce -> 2 atomics; done-protocol finalize.
// Replaces 3 kernels + all global bucket/offs/cursor/nCnt/Lsum traffic.
// ---------------------------------------------------------------------------
__global__ __launch_bounds__(512) void k_tail(const float* __restrict__ pred,
                                              const int* __restrict__ target,
                                              const int* __restrict__ am,
                                              const float* __restrict__ lse,
                                              const float* __restrict__ colsum,
                                              float* __restrict__ acc,
                                              int* __restrict__ done,
                                              float* __restrict__ out) {
    __shared__ int   tgam[PS];     // 16 KB: target | am<<16
    __shared__ float ldsLse[PS];   // 16 KB
    __shared__ int   sbucket[PS];  // 16 KB: s | am<<12
    __shared__ int   sc[PC];       // 2 KB
    __shared__ int   cur[PC];      // 2 KB
    __shared__ float red[8], redv[8], redk[8];

    const int b = blockIdx.x, t = threadIdx.x;
    cur[t] = 0;
    __syncthreads();

    float lacc = 0.0f;
    for (int i = t; i < PS; i += 512) {
        int gi = (b << 12) + i;
        int tg = target[gi];
        int a  = am[gi];
        float lv = lse[gi];
        tgam[i] = tg | (a << 16);
        ldsLse[i] = lv;
        lacc += lv;
        atomicAdd(&cur[tg], 1);    // LDS histogram
    }
    #pragma unroll
    for (int off = 1; off < 64; off <<= 1) lacc += __shfl_xor(lacc, off, 64);
    if ((t & 63) == 0) red[t >> 6] = lacc;
    __syncthreads();
    float Ls = red[0] + red[1] + red[2] + red[3] + red[4] + red[5] + red[6] + red[7];

    int x = cur[t];                // count for class t
    sc[t] = x;
    __syncthreads();
    for (int off = 1; off < PC; off <<= 1) {   // Hillis-Steele inclusive scan
        int v = (t >= off) ? sc[t - off] : 0;
        __syncthreads();
        sc[t] += v;
        __syncthreads();
    }
    int start = sc[t] - x;         // exclusive offset within batch
    cur[t] = start;
    __syncthreads();
    for (int i = t; i < PS; i += 512) {        // scatter from LDS only
        int e = tgam[i];
        int tg = e & 0xFFFF, a = e >> 16;
        int pos = atomicAdd(&cur[tg], 1);
        sbucket[pos] = i | (a << 12);
    }
    __syncthreads();

    int k = x;
    float val = 0.0f; int keep = 0;
    if (k > 0) {
        // mode of am over the bucket; tie -> smallest class (order-independent)
        int bc = 0, bvv = 0;
        for (int i = 0; i < k; ++i) {
            int v = sbucket[start + i] >> 12;
            int c = 0;
            for (int j = 0; j < k; ++j) c += ((sbucket[start + j] >> 12) == v) ? 1 : 0;
            if (c > bc || (c == bc && v < bvv)) { bc = c; bvv = v; }
        }
        int m = bvv;
        float lseSum = 0.0f, ep = 0.0f;
        for (int i = 0; i < k; ++i) {
            int s = sbucket[start + i] & (PS - 1);
            lseSum += ldsLse[s];
            ep += pred[(((size_t)(b << 12)) + s) * PC + m];   // scattered gather
        }
        float eq_sum = lseSum - ep;
        float ne_sum = (Ls - colsum[(b << 9) + m]) - eq_sum;
        float nf = (float)k;
        float eq_loss = eq_sum / fmaxf(nf, 1.0f);
        float ne_mean = ne_sum / fmaxf((float)PS - nf, 1.0f);
        float ne_loss = 1.0f / ((ne_mean != 0.0f) ? ne_mean : 1.0f);
        val = 0.5f * eq_loss + 0.5f * ne_loss;
        keep = (val != 0.0f) ? 1 : 0;
    }

    float vs = keep ? val : 0.0f;
    float ks = (float)keep;
    #pragma unroll
    for (int off = 1; off < 64; off <<= 1) {
        vs += __shfl_xor(vs, off, 64);
        ks += __shfl_xor(ks, off, 64);
    }
    if ((t & 63) == 0) { redv[t >> 6] = vs; redk[t >> 6] = ks; }
    __syncthreads();
    if (t == 0) {
        float sv = 0.0f, sk = 0.0f;
        #pragma unroll
        for (int i = 0; i < 8; ++i) { sv += redv[i]; sk += redk[i]; }
        atomicAdd(&acc[0], sv);
        atomicAdd(&acc[1], sk);
        __threadfence();
        int d = atomicAdd(done, 1);
        if (d == PB - 1) {                      // last batch-block finalizes
            __threadfence();
            float a0 = atomicAdd(&acc[0], 0.0f);
            float a1 = atomicAdd(&acc[1], 0.0f);
            out[0] = a0 / fmaxf(a1, 1.0f);
        }
    }
}

extern "C" void kernel_launch(void* const* d_in, const int* in_sizes, int n_in,
                              void* d_out, int out_size, void* d_ws, size_t ws_size,
                              hipStream_t stream) {
    const float* pred = (const float*)d_in[0];   // (B,S,C) f32
    const int* target = (const int*)d_in[1];     // (B,S) int
    float* out = (float*)d_out;

    char* w = (char*)d_ws;
    int*   am     = (int*)(w + 0);          // B*S ints   = 256 KiB
    float* lse    = (float*)(w + 262144);   // B*S floats = 256 KiB
    float* colsum = (float*)(w + 524288);   // B*C floats =  32 KiB
    float* acc    = (float*)(w + 557056);   // 2 floats
    int*   done   = (int*)(w + 557064);     // 1 int

    k0_init<<<32, 256, 0, stream>>>(colsum, acc, done);
    k1_rows<<<(PB * PS) / 16, 256, 0, stream>>>(pred, am, lse, colsum);
    k_tail<<<PB, 512, 0, stream>>>(pred, target, am, lse, colsum, acc, done, out);
}